// Round 2
// 276.742 us; speedup vs baseline: 1.0116x; 1.0116x over previous
//
#include <hip/hip_runtime.h>

// ConditionalFeedForward (gpt-fast MoE FFN), MI355X. fp32 in/out.
//   x[T][H], idx[T][K], gate[E][I][H], up[E][H][I], down[E][I][H]
//   hbuf[p][o] = silu(x.gate_row) * (x.down_row);  out[p][h] = hbuf[p].up_row
// R6 == R5 resubmit (R5 bench died on container acquisition, no counters).
// R5 theory: latency-bound (VALUBusy 13%, HBM 16% peak, 0 conflicts).
// Serialized chains removed vs R4:
//  (a) per-pair 6-level __shfl_xor butterfly inside the npl loop -> batched:
//      partials for a chunk of pairs first (32 independent x-loads in
//      flight), then one level-major butterfly over the whole chunk.
//  (b) thread0's serial 32-load idx scan -> one coalesced load + __ballot
//      + popc-prefix.
#define NE 8
#define HD 1024
#define IW 2816
#define NT 16
#define TK 2
#define NP (NT*TK)
#define NPC1 8   // pair chunk, phase 1
#define NPC2 8   // pair chunk, phase 2

// Phase 1: one wave per (expert, o-row). Gate+down row cached in regs (8KB),
// batched dot + single level-major butterfly per pair-chunk.
__global__ __launch_bounds__(256) void moe_phase1(
    const float* __restrict__ x,      // [NT][HD]
    const int*   __restrict__ idx,    // [NT][TK]
    const float* __restrict__ gate,   // [NE][IW][HD]
    const float* __restrict__ down,   // [NE][IW][HD]
    float*       __restrict__ hbuf)   // [NP][IW]
{
    __shared__ int s_list[NP];
    __shared__ int s_n;
    const int e = blockIdx.y;
    {
        const int t = threadIdx.x;
        const bool mine = (t < NP) && (idx[t] == e);
        const unsigned long long m = __ballot(mine);
        if (mine) s_list[__popcll(m & ((1ull << t) - 1ull))] = t;
        if (t == 0) s_n = (int)__popcll(m);
    }
    __syncthreads();
    const int npl = s_n;
    if (npl == 0) return;

    const int wave = threadIdx.x >> 6;
    const int lane = threadIdx.x & 63;
    const int o = blockIdx.x * 4 + wave;          // gridDim.x = IW/4 = 704

    const float* grow = gate + ((size_t)e * IW + o) * HD + lane * 4;
    const float* drow = down + ((size_t)e * IW + o) * HD + lane * 4;
    float gw[16], dw[16];
    #pragma unroll
    for (int c = 0; c < 4; ++c) {                  // HD = 4*256
        float4 gv = *(const float4*)(grow + c * 256);
        float4 dv = *(const float4*)(drow + c * 256);
        gw[4*c+0]=gv.x; gw[4*c+1]=gv.y; gw[4*c+2]=gv.z; gw[4*c+3]=gv.w;
        dw[4*c+0]=dv.x; dw[4*c+1]=dv.y; dw[4*c+2]=dv.z; dw[4*c+3]=dv.w;
    }

    for (int n0 = 0; n0 < npl; n0 += NPC1) {
        const int nc = (npl - n0 < NPC1) ? (npl - n0) : NPC1;
        float ag[NPC1], ad[NPC1];
        #pragma unroll
        for (int j = 0; j < NPC1; ++j) {
            ag[j] = 0.f; ad[j] = 0.f;
            if (j < nc) {                          // nc wave-uniform
                const float* xrow = x + (size_t)(s_list[n0 + j] >> 1) * HD + lane * 4;
                #pragma unroll
                for (int c = 0; c < 4; ++c) {
                    float4 xv = *(const float4*)(xrow + c * 256);
                    ag[j] += xv.x*gw[4*c+0] + xv.y*gw[4*c+1] + xv.z*gw[4*c+2] + xv.w*gw[4*c+3];
                    ad[j] += xv.x*dw[4*c+0] + xv.y*dw[4*c+1] + xv.z*dw[4*c+2] + xv.w*dw[4*c+3];
                }
            }
        }
        // level-major butterfly: 6 dependent levels TOTAL for the whole chunk,
        // 2*nc independent values pipeline through each level.
        #pragma unroll
        for (int off = 32; off > 0; off >>= 1) {
            #pragma unroll
            for (int j = 0; j < NPC1; ++j) {
                if (j < nc) {
                    ag[j] += __shfl_xor(ag[j], off, 64);
                    ad[j] += __shfl_xor(ad[j], off, 64);
                }
            }
        }
        if (lane == 0) {
            #pragma unroll
            for (int j = 0; j < NPC1; ++j) {
                if (j < nc) {
                    const float g = ag[j];
                    const float s = g / (1.f + __expf(-g));   // silu
                    hbuf[(size_t)s_list[n0 + j] * IW + o] = s * ad[j];
                }
            }
        }
    }
}

// Phase 2: one wave per (expert, h-row). Up row cached in regs (11KB),
// hbuf rows L2-resident; same batched-reduction structure.
__global__ __launch_bounds__(256) void moe_phase2(
    const float* __restrict__ up,     // [NE][HD][IW]
    const int*   __restrict__ idx,
    const float* __restrict__ hbuf,   // [NP][IW]
    float*       __restrict__ out)    // [NP][HD]
{
    __shared__ int s_list[NP];
    __shared__ int s_n;
    const int e = blockIdx.y;
    {
        const int t = threadIdx.x;
        const bool mine = (t < NP) && (idx[t] == e);
        const unsigned long long m = __ballot(mine);
        if (mine) s_list[__popcll(m & ((1ull << t) - 1ull))] = t;
        if (t == 0) s_n = (int)__popcll(m);
    }
    __syncthreads();
    const int npl = s_n;
    if (npl == 0) return;

    const int wave = threadIdx.x >> 6;
    const int lane = threadIdx.x & 63;
    const int h = blockIdx.x * 4 + wave;          // gridDim.x = HD/4 = 256

    const float* urow = up + ((size_t)e * HD + h) * IW + lane * 4;
    float w[44];                                   // IW = 11*256
    #pragma unroll
    for (int c = 0; c < 11; ++c) {
        float4 uv = *(const float4*)(urow + c * 256);
        w[4*c+0]=uv.x; w[4*c+1]=uv.y; w[4*c+2]=uv.z; w[4*c+3]=uv.w;
    }

    for (int n0 = 0; n0 < npl; n0 += NPC2) {
        const int nc = (npl - n0 < NPC2) ? (npl - n0) : NPC2;
        float acc[NPC2];
        #pragma unroll
        for (int j = 0; j < NPC2; ++j) {
            acc[j] = 0.f;
            if (j < nc) {
                const float* hrow = hbuf + (size_t)s_list[n0 + j] * IW + lane * 4;
                #pragma unroll
                for (int c = 0; c < 11; ++c) {
                    float4 hv = *(const float4*)(hrow + c * 256);
                    acc[j] += w[4*c+0]*hv.x + w[4*c+1]*hv.y + w[4*c+2]*hv.z + w[4*c+3]*hv.w;
                }
            }
        }
        #pragma unroll
        for (int off = 32; off > 0; off >>= 1) {
            #pragma unroll
            for (int j = 0; j < NPC2; ++j) {
                if (j < nc) acc[j] += __shfl_xor(acc[j], off, 64);
            }
        }
        if (lane == 0) {
            #pragma unroll
            for (int j = 0; j < NPC2; ++j) {
                if (j < nc) out[(size_t)s_list[n0 + j] * HD + h] = acc[j];
            }
        }
    }
}

extern "C" void kernel_launch(void* const* d_in, const int* in_sizes, int n_in,
                              void* d_out, int out_size, void* d_ws, size_t ws_size,
                              hipStream_t stream) {
    const float* x    = (const float*)d_in[0];
    const int*   idx  = (const int*)  d_in[1];
    const float* gate = (const float*)d_in[2];
    const float* up   = (const float*)d_in[3];
    const float* down = (const float*)d_in[4];
    float* hbuf = (float*)d_ws;              // 32*2816*4 = 360448 B scratch
    float* out  = (float*)d_out;             // [16][2][1024]

    moe_phase1<<<dim3(IW/4, NE), dim3(256), 0, stream>>>(x, idx, gate, down, hbuf);
    moe_phase2<<<dim3(HD/4, NE), dim3(256), 0, stream>>>(up, idx, hbuf, out);
}